// Round 1
// baseline (792.696 us; speedup 1.0000x reference)
//
#include <hip/hip_runtime.h>

#define BB 8192
#define DD 2048
#define NSLOT 7
#define NP1 (BB + 2*128)   // 8448
#define NP2 (BB + 4*128)   // 8704

typedef unsigned short u16;
typedef unsigned int   u32;

typedef __bf16 bf16x8 __attribute__((ext_vector_type(8)));
typedef float  f32x4  __attribute__((ext_vector_type(4)));

// ---- workspace layout (bytes). h1 reuses the xb region (xb dead after stage0).
#define OFF_WT   0ull
#define OFF_XB   (OFF_WT + (size_t)NSLOT*DD*DD*2)    // 58,720,256
#define OFF_H0   (OFF_XB + (size_t)BB*DD*2)          // 92,274,688
#define OFF_P1   (OFF_H0 + (size_t)BB*DD*2)          // 125,829,120
#define OFF_P2   (OFF_P1 + (size_t)NP1*4)
#define OFF_META (OFF_P2 + (size_t)NP2*4)
// meta ints: [0..1] cnt1, [2..5] cnt2, [6..7] cur1, [8..11] cur2,
//            [12..14] bases1, [15..19] bases2, [20] input-is-bf16 flag

__device__ __forceinline__ u16 f2bf(float f) {
  u32 u = __float_as_uint(f);
  u32 r = (u + 0x7FFFu + ((u >> 16) & 1u)) >> 16;
  return (u16)r;
}
__device__ __forceinline__ float bf2f(u16 u) {
  return __uint_as_float(((u32)u) << 16);
}

__device__ __forceinline__ void gld16(const void* g, void* l) {
  __builtin_amdgcn_global_load_lds(
      (const __attribute__((address_space(1))) void*)g,
      (__attribute__((address_space(3))) void*)l, 16, 0, 0);
}

// ---------------- setup kernels ----------------

__global__ void k_init(int* p1, int* p2, int* meta) {
  int i = blockIdx.x * 256 + threadIdx.x;
  if (i < NP1) p1[i] = -1;
  if (i < NP2) p2[i] = -1;
  if (i < 20) meta[i] = 0;
}

// Decide whether buffers are bf16-stored or fp32-stored.
// true bf16 N(0,1) data: ~all shorts have sane exponent, ~none are exactly 0.
// fp32 storage: half the shorts are fp32 low-halves -> garbage exponents or zeros.
__global__ void k_detect(const u16* x, int* meta) {
  __shared__ int cnt, cntz;
  if (threadIdx.x == 0) { cnt = 0; cntz = 0; }
  __syncthreads();
  u16 u = x[threadIdx.x * 17];       // odd stride mixes both parities
  int ex = (u >> 7) & 0xFF;
  int sane = (ex == 0) || (ex >= 112 && ex <= 143);
  atomicAdd(&cnt, sane);
  atomicAdd(&cntz, (u == 0) ? 1 : 0);
  __syncthreads();
  if (threadIdx.x == 0) meta[20] = (cnt >= 205 && cntz < 64) ? 1 : 0;
}

__global__ void k_count(const int* pm, int* meta) {
  int b = blockIdx.x * 256 + threadIdx.x;
  if (b >= BB) return;
  int b0 = pm[b*3] & 1, b1 = pm[b*3+1] & 1;
  atomicAdd(&meta[b0], 1);
  atomicAdd(&meta[2 + b0*2 + b1], 1);
}

__global__ void k_bases(int* meta) {
  if (threadIdx.x || blockIdx.x) return;
  meta[12] = 0;
  meta[13] = (meta[0] + 127) & ~127;
  meta[14] = meta[13] + ((meta[1] + 127) & ~127);
  int base = 0;
  meta[15] = 0;
  for (int e = 0; e < 4; ++e) {
    base += (meta[2+e] + 127) & ~127;
    meta[16+e] = base;
  }
}

__global__ void k_fill(const int* pm, int* p1, int* p2, int* meta) {
  int b = blockIdx.x * 256 + threadIdx.x;
  if (b >= BB) return;
  int b0 = pm[b*3] & 1, b1 = pm[b*3+1] & 1;
  int s1 = atomicAdd(&meta[6 + b0], 1);
  p1[meta[12 + b0] + s1] = b;
  int leaf = b0*2 + b1;
  int s2 = atomicAdd(&meta[8 + leaf], 1);
  p2[meta[15 + leaf] + s2] = b;
}

// x -> bf16 (copy if already bf16)
__global__ void k_cvtx(const void* __restrict__ x, u16* __restrict__ xb,
                       const int* __restrict__ meta) {
  int i = blockIdx.x * 256 + threadIdx.x;   // over BB*DD/8 chunks of 8 elems
  if (meta[20]) {
    ((uint4*)xb)[i] = ((const uint4*)x)[i];
  } else {
    const float4* p = (const float4*)x + (size_t)i * 2;
    float4 a = p[0], b = p[1];
    uint4 o;
    o.x = f2bf(a.x) | ((u32)f2bf(a.y) << 16);
    o.y = f2bf(a.z) | ((u32)f2bf(a.w) << 16);
    o.z = f2bf(b.x) | ((u32)f2bf(b.y) << 16);
    o.w = f2bf(b.z) | ((u32)f2bf(b.w) << 16);
    ((uint4*)xb)[i] = o;
  }
}

// transpose+convert weights into 7 slots of Wt[n][k] bf16
__global__ void k_wt(const void* __restrict__ W0, const void* __restrict__ W1,
                     const void* __restrict__ W2, u16* __restrict__ wt,
                     const int* __restrict__ meta) {
  __shared__ float tile[64][65];
  int bid = blockIdx.x;
  int slot = bid >> 10;          // 1024 tiles per slot (32x32 of 64x64)
  int t = bid & 1023;
  int tr = t >> 5, tc = t & 31;
  const void* src; size_t eoff;
  if (slot == 0)      { src = W0; eoff = 0; }
  else if (slot <= 2) { src = W1; eoff = (size_t)(slot-1)*DD*DD; }
  else                { src = W2; eoff = (size_t)(slot-3)*DD*DD; }
  int r0 = tr*64, c0 = tc*64;
  int tid = threadIdx.x;
  int isbf = meta[20];
  #pragma unroll
  for (int i = 0; i < 4; ++i) {
    int idx = tid + i*256;
    int r = idx >> 4, c4 = (idx & 15) * 4;
    size_t goff = eoff + (size_t)(r0 + r)*DD + c0 + c4;
    if (isbf) {
      ushort4 v = *(const ushort4*)((const u16*)src + goff);
      tile[r][c4+0] = bf2f(v.x); tile[r][c4+1] = bf2f(v.y);
      tile[r][c4+2] = bf2f(v.z); tile[r][c4+3] = bf2f(v.w);
    } else {
      float4 v = *(const float4*)((const float*)src + goff);
      tile[r][c4+0] = v.x; tile[r][c4+1] = v.y;
      tile[r][c4+2] = v.z; tile[r][c4+3] = v.w;
    }
  }
  __syncthreads();
  u16* dst = wt + (size_t)slot*DD*DD;
  #pragma unroll
  for (int i = 0; i < 4; ++i) {
    int idx = tid + i*256;
    int orow = idx >> 4, oc = (idx & 15) * 4;   // orow = n, oc = k (within tile)
    uint2 o;
    o.x = f2bf(tile[oc+0][orow]) | ((u32)f2bf(tile[oc+1][orow]) << 16);
    o.y = f2bf(tile[oc+2][orow]) | ((u32)f2bf(tile[oc+3][orow]) << 16);
    *(uint2*)&dst[(size_t)(c0 + orow)*DD + r0 + oc] = o;
  }
}

// ---------------- GEMM: C = relu(A @ W + bias), expert-routed ----------------
// A: bf16 [BB x DD] original row order. Wt: bf16 slots of [n][k] (pre-offset).
// perm: tile rows -> original rows (gather for A, scatter for Out); null=identity.
// bases: group start offsets (128-aligned) for expert lookup; nexp in {1,2,4}.
__global__ __launch_bounds__(256, 2) void k_gemm(
    const u16* __restrict__ A, const u16* __restrict__ Wt,
    const void* __restrict__ bias, const int* __restrict__ perm,
    const int* __restrict__ bases, int nexp,
    void* __restrict__ Out, int final_out, const int* __restrict__ meta) {
  __shared__ __align__(16) u16 As[128*32];
  __shared__ __align__(16) u16 Bs[128*32];

  const int tid  = threadIdx.x;
  const int wid  = tid >> 6;
  const int lane = tid & 63;
  const int m0 = blockIdx.x * 128;
  const int n0 = blockIdx.y * 128;

  int e = 0;
  if (nexp == 2)      e = (m0 >= bases[1]);
  else if (nexp == 4) e = (m0 >= bases[1]) + (m0 >= bases[2]) + (m0 >= bases[3]);
  const u16* W = Wt + (size_t)e * DD * DD;

  // staging geometry: 8 segments of 1024B per tile; wave w pass p -> seg p*4+w.
  // lane writes LDS byte [seg*1024 + lane*16]; row = off>>6, kelem = (off&63)>>1
  const u16* gA[2]; const u16* gB[2];
  u16* lA[2]; u16* lB[2];
  #pragma unroll
  for (int p = 0; p < 2; ++p) {
    int seg  = p*4 + wid;
    int boff = seg*1024 + lane*16;
    int row  = boff >> 6;
    int kk   = (boff & 63) >> 1;
    int gr = m0 + row;
    if (perm) { int t = perm[gr]; gr = (t < 0) ? 0 : t; }
    gA[p] = A + (size_t)gr * DD + kk;
    gB[p] = W + (size_t)(n0 + row) * DD + kk;
    lA[p] = (u16*)((char*)As + seg*1024);
    lB[p] = (u16*)((char*)Bs + seg*1024);
  }

  f32x4 zero = {0.0f, 0.0f, 0.0f, 0.0f};
  f32x4 acc[4][4];
  #pragma unroll
  for (int i = 0; i < 4; ++i)
    #pragma unroll
    for (int j = 0; j < 4; ++j) acc[i][j] = zero;

  const int wm = wid & 1, wn = wid >> 1;
  const int q = lane >> 4, cl = lane & 15;
  const int aoff = (wm*64 + cl) * 32 + q*8;
  const int boff2 = (wn*64 + cl) * 32 + q*8;

  for (int k0 = 0; k0 < DD; k0 += 32) {
    gld16(gA[0] + k0, lA[0]);
    gld16(gA[1] + k0, lA[1]);
    gld16(gB[0] + k0, lB[0]);
    gld16(gB[1] + k0, lB[1]);
    __syncthreads();   // drains vmcnt -> staging complete
    bf16x8 af[4], bf[4];
    #pragma unroll
    for (int mt = 0; mt < 4; ++mt) af[mt] = *(const bf16x8*)&As[aoff + mt*16*32];
    #pragma unroll
    for (int nt = 0; nt < 4; ++nt) bf[nt] = *(const bf16x8*)&Bs[boff2 + nt*16*32];
    #pragma unroll
    for (int mt = 0; mt < 4; ++mt)
      #pragma unroll
      for (int nt = 0; nt < 4; ++nt)
        acc[mt][nt] = __builtin_amdgcn_mfma_f32_16x16x32_bf16(af[mt], bf[nt], acc[mt][nt], 0, 0, 0);
    __syncthreads();   // all reads done before next stage overwrites
  }

  const int isbf = meta[20];
  float bv[4];
  #pragma unroll
  for (int nt = 0; nt < 4; ++nt) {
    int col = n0 + wn*64 + nt*16 + cl;
    bv[nt] = isbf ? bf2f(((const u16*)bias)[e*DD + col])
                  : ((const float*)bias)[e*DD + col];
  }
  #pragma unroll
  for (int mt = 0; mt < 4; ++mt) {
    int rbase = m0 + wm*64 + mt*16 + q*4;
    #pragma unroll
    for (int r = 0; r < 4; ++r) {
      int row = rbase + r;
      int orow = row;
      if (perm) { orow = perm[row]; if (orow < 0) continue; }
      #pragma unroll
      for (int nt = 0; nt < 4; ++nt) {
        int col = n0 + wn*64 + nt*16 + cl;
        float v = acc[mt][nt][r] + bv[nt];
        v = v > 0.0f ? v : 0.0f;
        if (!final_out || isbf) ((u16*)Out)[(size_t)orow*DD + col] = f2bf(v);
        else                    ((float*)Out)[(size_t)orow*DD + col] = v;
      }
    }
  }
}

extern "C" void kernel_launch(void* const* d_in, const int* in_sizes, int n_in,
                              void* d_out, int out_size, void* d_ws, size_t ws_size,
                              hipStream_t stream) {
  (void)in_sizes; (void)n_in; (void)out_size; (void)ws_size;
  const void* x  = d_in[0];
  const void* W0 = d_in[1];
  const void* b0 = d_in[2];
  const void* W1 = d_in[3];
  const void* b1 = d_in[4];
  const void* W2 = d_in[5];
  const void* b2 = d_in[6];
  const int*  pm = (const int*)d_in[7];

  char* ws  = (char*)d_ws;
  u16*  wt  = (u16*)(ws + OFF_WT);
  u16*  xb  = (u16*)(ws + OFF_XB);   // also reused as h1 after stage0
  u16*  h0  = (u16*)(ws + OFF_H0);
  u16*  h1  = xb;
  int*  p1  = (int*)(ws + OFF_P1);
  int*  p2  = (int*)(ws + OFF_P2);
  int*  meta= (int*)(ws + OFF_META);

  hipLaunchKernelGGL(k_init,   dim3(34), dim3(256), 0, stream, p1, p2, meta);
  hipLaunchKernelGGL(k_detect, dim3(1),  dim3(256), 0, stream, (const u16*)x, meta);
  hipLaunchKernelGGL(k_count,  dim3(32), dim3(256), 0, stream, pm, meta);
  hipLaunchKernelGGL(k_bases,  dim3(1),  dim3(1),   0, stream, meta);
  hipLaunchKernelGGL(k_fill,   dim3(32), dim3(256), 0, stream, pm, p1, p2, meta);
  hipLaunchKernelGGL(k_cvtx,   dim3(BB*DD/8/256), dim3(256), 0, stream, x, xb, meta);
  hipLaunchKernelGGL(k_wt,     dim3(7*1024), dim3(256), 0, stream, W0, W1, W2, wt, meta);

  // stage 0: h0 = relu(x @ W0 + b0)
  hipLaunchKernelGGL(k_gemm, dim3(64, 16), dim3(256), 0, stream,
                     xb, wt, b0, (const int*)nullptr, (const int*)nullptr, 1,
                     (void*)h0, 0, meta);
  // stage 1: h1 = relu(h0 @ W1[bit0] + b1[bit0]), rows grouped by bit0
  hipLaunchKernelGGL(k_gemm, dim3(66, 16), dim3(256), 0, stream,
                     h0, wt + (size_t)1*DD*DD, b1, p1, meta + 12, 2,
                     (void*)h1, 0, meta);
  // stage 2: y = relu(h1 @ W2[leaf] + b2[leaf]), rows grouped by leaf
  hipLaunchKernelGGL(k_gemm, dim3(68, 16), dim3(256), 0, stream,
                     h1, wt + (size_t)3*DD*DD, b2, p2, meta + 15, 4,
                     d_out, 1, meta);
}

// Round 2
// 568.135 us; speedup vs baseline: 1.3953x; 1.3953x over previous
//
#include <hip/hip_runtime.h>

#define BB 8192
#define DD 2048
#define NSLOT 7
#define NP1 (BB + 2*128)   // 8448
#define NP2 (BB + 4*128)   // 8704

typedef unsigned short u16;
typedef unsigned int   u32;
typedef unsigned long long u64;

typedef __bf16 bf16x8 __attribute__((ext_vector_type(8)));
typedef float  f32x4  __attribute__((ext_vector_type(4)));

// ---- workspace layout (bytes). h1 reuses the xb region (xb dead after stage0).
#define OFF_WT   0ull
#define OFF_XB   (OFF_WT + (size_t)NSLOT*DD*DD*2)    // 58,720,256
#define OFF_H0   (OFF_XB + (size_t)BB*DD*2)          // 92,274,688
#define OFF_P1   (OFF_H0 + (size_t)BB*DD*2)          // 125,829,120
#define OFF_P2   (OFF_P1 + (size_t)NP1*4)
#define OFF_META (OFF_P2 + (size_t)NP2*4)
// meta ints: [12..14] bases1, [15..19] bases2, [20] input-is-bf16 flag

__device__ __forceinline__ u16 f2bf(float f) {
  u32 u = __float_as_uint(f);
  u32 r = (u + 0x7FFFu + ((u >> 16) & 1u)) >> 16;
  return (u16)r;
}
__device__ __forceinline__ float bf2f(u16 u) {
  return __uint_as_float(((u32)u) << 16);
}

__device__ __forceinline__ void gld16(const void* g, void* l) {
  __builtin_amdgcn_global_load_lds(
      (const __attribute__((address_space(1))) void*)g,
      (__attribute__((address_space(3))) void*)l, 16, 0, 0);
}

// ---------------- setup kernels ----------------

// Decide whether buffers are bf16-stored or fp32-stored.
__global__ void k_detect(const u16* x, int* meta) {
  __shared__ int cnt, cntz;
  if (threadIdx.x == 0) { cnt = 0; cntz = 0; }
  __syncthreads();
  u16 u = x[threadIdx.x * 17];       // odd stride mixes both parities
  int ex = (u >> 7) & 0xFF;
  int sane = (ex == 0) || (ex >= 112 && ex <= 143);
  atomicAdd(&cnt, sane);
  atomicAdd(&cntz, (u == 0) ? 1 : 0);
  __syncthreads();
  if (threadIdx.x == 0) meta[20] = (cnt >= 205 && cntz < 64) ? 1 : 0;
}

// Single-block routing: count via wave ballots (LDS atomics once per wave),
// 128-align group bases, fill perms with ballot-prefix slot assignment.
// Replaces k_init/k_count/k_bases/k_fill (which died on contended device atomics).
__global__ __launch_bounds__(1024) void k_route(const int* __restrict__ pm,
                                                int* __restrict__ p1,
                                                int* __restrict__ p2,
                                                int* __restrict__ meta) {
  __shared__ int cnt[6];            // [0..1] stage1, [2..5] stage2
  __shared__ int cur[6];
  __shared__ int base1[2], base2[4];
  const int tid = threadIdx.x;
  const int lane = tid & 63;
  if (tid < 6) { cnt[tid] = 0; cur[tid] = 0; }
  __syncthreads();

  // init padding marker
  for (int i = tid; i < NP1; i += 1024) p1[i] = -1;
  for (int i = tid; i < NP2; i += 1024) p2[i] = -1;

  int myb0[8], myleaf[8];
  #pragma unroll
  for (int i = 0; i < 8; ++i) {
    int b = i * 1024 + tid;
    int b0 = pm[b*3] & 1, b1 = pm[b*3+1] & 1;
    myb0[i] = b0; myleaf[i] = b0*2 + b1;
  }
  // count: one LDS atomic per wave per expert
  #pragma unroll
  for (int i = 0; i < 8; ++i) {
    u64 m0 = __ballot(myb0[i] == 0);
    if (lane == 0) {
      atomicAdd(&cnt[0], __popcll(m0));
      atomicAdd(&cnt[1], 64 - __popcll(m0));
    }
    #pragma unroll
    for (int e = 0; e < 4; ++e) {
      u64 me = __ballot(myleaf[i] == e);
      if (lane == 0) atomicAdd(&cnt[2+e], __popcll(me));
    }
  }
  __syncthreads();
  if (tid == 0) {
    base1[0] = 0;
    base1[1] = (cnt[0] + 127) & ~127;
    meta[12] = 0; meta[13] = base1[1];
    meta[14] = base1[1] + ((cnt[1] + 127) & ~127);
    int b = 0;
    #pragma unroll
    for (int e = 0; e < 4; ++e) {
      base2[e] = b; meta[15+e] = b;
      b += (cnt[2+e] + 127) & ~127;
    }
    meta[19] = b;
  }
  __syncthreads();
  // fill: ballot-prefix within wave, one LDS atomic per wave per group
  #pragma unroll
  for (int i = 0; i < 8; ++i) {
    int b = i * 1024 + tid;
    u64 lt = (1ull << lane) - 1ull;
    #pragma unroll
    for (int g = 0; g < 2; ++g) {
      u64 m = __ballot(myb0[i] == g);
      int pos = __popcll(m & lt);
      int wbase = 0;
      if (lane == 0 && m) wbase = atomicAdd(&cur[g], __popcll(m));
      wbase = __shfl(wbase, 0);
      if (myb0[i] == g) p1[base1[g] + wbase + pos] = b;
    }
    #pragma unroll
    for (int g = 0; g < 4; ++g) {
      u64 m = __ballot(myleaf[i] == g);
      int pos = __popcll(m & lt);
      int wbase = 0;
      if (lane == 0 && m) wbase = atomicAdd(&cur[2+g], __popcll(m));
      wbase = __shfl(wbase, 0);
      if (myleaf[i] == g) p2[base2[g] + wbase + pos] = b;
    }
  }
}

// x -> bf16 (copy if already bf16)
__global__ void k_cvtx(const void* __restrict__ x, u16* __restrict__ xb,
                       const int* __restrict__ meta) {
  int i = blockIdx.x * 256 + threadIdx.x;   // over BB*DD/8 chunks of 8 elems
  if (meta[20]) {
    ((uint4*)xb)[i] = ((const uint4*)x)[i];
  } else {
    const float4* p = (const float4*)x + (size_t)i * 2;
    float4 a = p[0], b = p[1];
    uint4 o;
    o.x = f2bf(a.x) | ((u32)f2bf(a.y) << 16);
    o.y = f2bf(a.z) | ((u32)f2bf(a.w) << 16);
    o.z = f2bf(b.x) | ((u32)f2bf(b.y) << 16);
    o.w = f2bf(b.z) | ((u32)f2bf(b.w) << 16);
    ((uint4*)xb)[i] = o;
  }
}

// transpose+convert weights into 7 slots of Wt[n][k] bf16
__global__ void k_wt(const void* __restrict__ W0, const void* __restrict__ W1,
                     const void* __restrict__ W2, u16* __restrict__ wt,
                     const int* __restrict__ meta) {
  __shared__ float tile[64][65];
  int bid = blockIdx.x;
  int slot = bid >> 10;          // 1024 tiles per slot (32x32 of 64x64)
  int t = bid & 1023;
  int tr = t >> 5, tc = t & 31;
  const void* src; size_t eoff;
  if (slot == 0)      { src = W0; eoff = 0; }
  else if (slot <= 2) { src = W1; eoff = (size_t)(slot-1)*DD*DD; }
  else                { src = W2; eoff = (size_t)(slot-3)*DD*DD; }
  int r0 = tr*64, c0 = tc*64;
  int tid = threadIdx.x;
  int isbf = meta[20];
  #pragma unroll
  for (int i = 0; i < 4; ++i) {
    int idx = tid + i*256;
    int r = idx >> 4, c4 = (idx & 15) * 4;
    size_t goff = eoff + (size_t)(r0 + r)*DD + c0 + c4;
    if (isbf) {
      ushort4 v = *(const ushort4*)((const u16*)src + goff);
      tile[r][c4+0] = bf2f(v.x); tile[r][c4+1] = bf2f(v.y);
      tile[r][c4+2] = bf2f(v.z); tile[r][c4+3] = bf2f(v.w);
    } else {
      float4 v = *(const float4*)((const float*)src + goff);
      tile[r][c4+0] = v.x; tile[r][c4+1] = v.y;
      tile[r][c4+2] = v.z; tile[r][c4+3] = v.w;
    }
  }
  __syncthreads();
  u16* dst = wt + (size_t)slot*DD*DD;
  #pragma unroll
  for (int i = 0; i < 4; ++i) {
    int idx = tid + i*256;
    int orow = idx >> 4, oc = (idx & 15) * 4;   // orow = n, oc = k (within tile)
    uint2 o;
    o.x = f2bf(tile[oc+0][orow]) | ((u32)f2bf(tile[oc+1][orow]) << 16);
    o.y = f2bf(tile[oc+2][orow]) | ((u32)f2bf(tile[oc+3][orow]) << 16);
    *(uint2*)&dst[(size_t)(c0 + orow)*DD + r0 + oc] = o;
  }
}

// ---------------- GEMM: C = relu(A @ W + bias), expert-routed ----------------
__global__ __launch_bounds__(256, 2) void k_gemm(
    const u16* __restrict__ A, const u16* __restrict__ Wt,
    const void* __restrict__ bias, const int* __restrict__ perm,
    const int* __restrict__ bases, int nexp,
    void* __restrict__ Out, int final_out, const int* __restrict__ meta) {
  __shared__ __align__(16) u16 As[128*32];
  __shared__ __align__(16) u16 Bs[128*32];

  const int tid  = threadIdx.x;
  const int wid  = tid >> 6;
  const int lane = tid & 63;
  const int m0 = blockIdx.x * 128;
  const int n0 = blockIdx.y * 128;

  int e = 0;
  if (nexp == 2)      e = (m0 >= bases[1]);
  else if (nexp == 4) e = (m0 >= bases[1]) + (m0 >= bases[2]) + (m0 >= bases[3]);
  const u16* W = Wt + (size_t)e * DD * DD;

  // staging geometry: 8 segments of 1024B per tile; wave w pass p -> seg p*4+w.
  const u16* gA[2]; const u16* gB[2];
  u16* lA[2]; u16* lB[2];
  #pragma unroll
  for (int p = 0; p < 2; ++p) {
    int seg  = p*4 + wid;
    int boff = seg*1024 + lane*16;
    int row  = boff >> 6;
    int kk   = (boff & 63) >> 1;
    int gr = m0 + row;
    if (perm) { int t = perm[gr]; gr = (t < 0) ? 0 : t; }
    gA[p] = A + (size_t)gr * DD + kk;
    gB[p] = W + (size_t)(n0 + row) * DD + kk;
    lA[p] = (u16*)((char*)As + seg*1024);
    lB[p] = (u16*)((char*)Bs + seg*1024);
  }

  f32x4 zero = {0.0f, 0.0f, 0.0f, 0.0f};
  f32x4 acc[4][4];
  #pragma unroll
  for (int i = 0; i < 4; ++i)
    #pragma unroll
    for (int j = 0; j < 4; ++j) acc[i][j] = zero;

  const int wm = wid & 1, wn = wid >> 1;
  const int q = lane >> 4, cl = lane & 15;
  const int aoff = (wm*64 + cl) * 32 + q*8;
  const int boff2 = (wn*64 + cl) * 32 + q*8;

  for (int k0 = 0; k0 < DD; k0 += 32) {
    gld16(gA[0] + k0, lA[0]);
    gld16(gA[1] + k0, lA[1]);
    gld16(gB[0] + k0, lB[0]);
    gld16(gB[1] + k0, lB[1]);
    __syncthreads();   // drains vmcnt -> staging complete
    bf16x8 af[4], bf[4];
    #pragma unroll
    for (int mt = 0; mt < 4; ++mt) af[mt] = *(const bf16x8*)&As[aoff + mt*16*32];
    #pragma unroll
    for (int nt = 0; nt < 4; ++nt) bf[nt] = *(const bf16x8*)&Bs[boff2 + nt*16*32];
    #pragma unroll
    for (int mt = 0; mt < 4; ++mt)
      #pragma unroll
      for (int nt = 0; nt < 4; ++nt)
        acc[mt][nt] = __builtin_amdgcn_mfma_f32_16x16x32_bf16(af[mt], bf[nt], acc[mt][nt], 0, 0, 0);
    __syncthreads();   // all reads done before next stage overwrites
  }

  const int isbf = meta[20];
  float bv[4];
  #pragma unroll
  for (int nt = 0; nt < 4; ++nt) {
    int col = n0 + wn*64 + nt*16 + cl;
    bv[nt] = isbf ? bf2f(((const u16*)bias)[e*DD + col])
                  : ((const float*)bias)[e*DD + col];
  }
  #pragma unroll
  for (int mt = 0; mt < 4; ++mt) {
    int rbase = m0 + wm*64 + mt*16 + q*4;
    #pragma unroll
    for (int r = 0; r < 4; ++r) {
      int row = rbase + r;
      int orow = row;
      if (perm) { orow = perm[row]; if (orow < 0) continue; }
      #pragma unroll
      for (int nt = 0; nt < 4; ++nt) {
        int col = n0 + wn*64 + nt*16 + cl;
        float v = acc[mt][nt][r] + bv[nt];
        v = v > 0.0f ? v : 0.0f;
        if (!final_out || isbf) ((u16*)Out)[(size_t)orow*DD + col] = f2bf(v);
        else                    ((float*)Out)[(size_t)orow*DD + col] = v;
      }
    }
  }
}

extern "C" void kernel_launch(void* const* d_in, const int* in_sizes, int n_in,
                              void* d_out, int out_size, void* d_ws, size_t ws_size,
                              hipStream_t stream) {
  (void)in_sizes; (void)n_in; (void)out_size; (void)ws_size;
  const void* x  = d_in[0];
  const void* W0 = d_in[1];
  const void* b0 = d_in[2];
  const void* W1 = d_in[3];
  const void* b1 = d_in[4];
  const void* W2 = d_in[5];
  const void* b2 = d_in[6];
  const int*  pm = (const int*)d_in[7];

  char* ws  = (char*)d_ws;
  u16*  wt  = (u16*)(ws + OFF_WT);
  u16*  xb  = (u16*)(ws + OFF_XB);   // also reused as h1 after stage0
  u16*  h0  = (u16*)(ws + OFF_H0);
  u16*  h1  = xb;
  int*  p1  = (int*)(ws + OFF_P1);
  int*  p2  = (int*)(ws + OFF_P2);
  int*  meta= (int*)(ws + OFF_META);

  hipLaunchKernelGGL(k_detect, dim3(1),  dim3(256),  0, stream, (const u16*)x, meta);
  hipLaunchKernelGGL(k_route,  dim3(1),  dim3(1024), 0, stream, pm, p1, p2, meta);
  hipLaunchKernelGGL(k_cvtx,   dim3(BB*DD/8/256), dim3(256), 0, stream, x, xb, meta);
  hipLaunchKernelGGL(k_wt,     dim3(7*1024), dim3(256), 0, stream, W0, W1, W2, wt, meta);

  // stage 0: h0 = relu(x @ W0 + b0)
  hipLaunchKernelGGL(k_gemm, dim3(64, 16), dim3(256), 0, stream,
                     xb, wt, b0, (const int*)nullptr, (const int*)nullptr, 1,
                     (void*)h0, 0, meta);
  // stage 1: h1 = relu(h0 @ W1[bit0] + b1[bit0]), rows grouped by bit0
  hipLaunchKernelGGL(k_gemm, dim3(66, 16), dim3(256), 0, stream,
                     h0, wt + (size_t)1*DD*DD, b1, p1, meta + 12, 2,
                     (void*)h1, 0, meta);
  // stage 2: y = relu(h1 @ W2[leaf] + b2[leaf]), rows grouped by leaf
  hipLaunchKernelGGL(k_gemm, dim3(68, 16), dim3(256), 0, stream,
                     h1, wt + (size_t)3*DD*DD, b2, p2, meta + 15, 4,
                     d_out, 1, meta);
}

// Round 3
// 540.807 us; speedup vs baseline: 1.4658x; 1.0505x over previous
//
#include <hip/hip_runtime.h>

#define BB 8192
#define DD 2048
#define NSLOT 7
#define NP1 (BB + 2*128)   // 8448
#define NP2 (BB + 4*128)   // 8704

typedef unsigned short u16;
typedef unsigned int   u32;
typedef unsigned long long u64;

typedef __bf16 bf16x8 __attribute__((ext_vector_type(8)));
typedef float  f32x4  __attribute__((ext_vector_type(4)));
typedef u16    u16x8  __attribute__((ext_vector_type(8)));

// ---- workspace layout (bytes). h1 reuses the xb region (xb dead after stage0).
#define OFF_WT   0ull
#define OFF_XB   (OFF_WT + (size_t)NSLOT*DD*DD*2)    // 58,720,256
#define OFF_H0   (OFF_XB + (size_t)BB*DD*2)          // 92,274,688
#define OFF_P1   (OFF_H0 + (size_t)BB*DD*2)          // 125,829,120
#define OFF_P2   (OFF_P1 + (size_t)NP1*4)
#define OFF_META (OFF_P2 + (size_t)NP2*4)
// meta ints: [12..14] bases1, [15..19] bases2, [20] input-is-bf16 flag

__device__ __forceinline__ u16 f2bf(float f) {
  u32 u = __float_as_uint(f);
  u32 r = (u + 0x7FFFu + ((u >> 16) & 1u)) >> 16;
  return (u16)r;
}
__device__ __forceinline__ float bf2f(u16 u) {
  return __uint_as_float(((u32)u) << 16);
}

__device__ __forceinline__ void gld16(const void* g, void* l) {
  __builtin_amdgcn_global_load_lds(
      (const __attribute__((address_space(1))) void*)g,
      (__attribute__((address_space(3))) void*)l, 16, 0, 0);
}

// ---------------- setup kernels ----------------

// Decide whether buffers are bf16-stored or fp32-stored.
__global__ void k_detect(const u16* x, int* meta) {
  __shared__ int cnt, cntz;
  if (threadIdx.x == 0) { cnt = 0; cntz = 0; }
  __syncthreads();
  u16 u = x[threadIdx.x * 17];       // odd stride mixes both parities
  int ex = (u >> 7) & 0xFF;
  int sane = (ex == 0) || (ex >= 112 && ex <= 143);
  atomicAdd(&cnt, sane);
  atomicAdd(&cntz, (u == 0) ? 1 : 0);
  __syncthreads();
  if (threadIdx.x == 0) meta[20] = (cnt >= 205 && cntz < 64) ? 1 : 0;
}

// Single-block routing: count via wave ballots (LDS atomics once per wave),
// 128-align group bases, fill perms with ballot-prefix slot assignment.
__global__ __launch_bounds__(1024) void k_route(const int* __restrict__ pm,
                                                int* __restrict__ p1,
                                                int* __restrict__ p2,
                                                int* __restrict__ meta) {
  __shared__ int cnt[6];            // [0..1] stage1, [2..5] stage2
  __shared__ int cur[6];
  __shared__ int base1[2], base2[4];
  const int tid = threadIdx.x;
  const int lane = tid & 63;
  if (tid < 6) { cnt[tid] = 0; cur[tid] = 0; }
  __syncthreads();

  for (int i = tid; i < NP1; i += 1024) p1[i] = -1;
  for (int i = tid; i < NP2; i += 1024) p2[i] = -1;

  int myb0[8], myleaf[8];
  #pragma unroll
  for (int i = 0; i < 8; ++i) {
    int b = i * 1024 + tid;
    int b0 = pm[b*3] & 1, b1 = pm[b*3+1] & 1;
    myb0[i] = b0; myleaf[i] = b0*2 + b1;
  }
  #pragma unroll
  for (int i = 0; i < 8; ++i) {
    u64 m0 = __ballot(myb0[i] == 0);
    if (lane == 0) {
      atomicAdd(&cnt[0], __popcll(m0));
      atomicAdd(&cnt[1], 64 - __popcll(m0));
    }
    #pragma unroll
    for (int e = 0; e < 4; ++e) {
      u64 me = __ballot(myleaf[i] == e);
      if (lane == 0) atomicAdd(&cnt[2+e], __popcll(me));
    }
  }
  __syncthreads();
  if (tid == 0) {
    base1[0] = 0;
    base1[1] = (cnt[0] + 127) & ~127;
    meta[12] = 0; meta[13] = base1[1];
    meta[14] = base1[1] + ((cnt[1] + 127) & ~127);
    int b = 0;
    #pragma unroll
    for (int e = 0; e < 4; ++e) {
      base2[e] = b; meta[15+e] = b;
      b += (cnt[2+e] + 127) & ~127;
    }
    meta[19] = b;
  }
  __syncthreads();
  #pragma unroll
  for (int i = 0; i < 8; ++i) {
    int b = i * 1024 + tid;
    u64 lt = (1ull << lane) - 1ull;
    #pragma unroll
    for (int g = 0; g < 2; ++g) {
      u64 m = __ballot(myb0[i] == g);
      int pos = __popcll(m & lt);
      int wbase = 0;
      if (lane == 0 && m) wbase = atomicAdd(&cur[g], __popcll(m));
      wbase = __shfl(wbase, 0);
      if (myb0[i] == g) p1[base1[g] + wbase + pos] = b;
    }
    #pragma unroll
    for (int g = 0; g < 4; ++g) {
      u64 m = __ballot(myleaf[i] == g);
      int pos = __popcll(m & lt);
      int wbase = 0;
      if (lane == 0 && m) wbase = atomicAdd(&cur[2+g], __popcll(m));
      wbase = __shfl(wbase, 0);
      if (myleaf[i] == g) p2[base2[g] + wbase + pos] = b;
    }
  }
}

// x -> bf16 (copy if already bf16)
__global__ void k_cvtx(const void* __restrict__ x, u16* __restrict__ xb,
                       const int* __restrict__ meta) {
  int i = blockIdx.x * 256 + threadIdx.x;
  if (meta[20]) {
    ((uint4*)xb)[i] = ((const uint4*)x)[i];
  } else {
    const float4* p = (const float4*)x + (size_t)i * 2;
    float4 a = p[0], b = p[1];
    uint4 o;
    o.x = f2bf(a.x) | ((u32)f2bf(a.y) << 16);
    o.y = f2bf(a.z) | ((u32)f2bf(a.w) << 16);
    o.z = f2bf(b.x) | ((u32)f2bf(b.y) << 16);
    o.w = f2bf(b.z) | ((u32)f2bf(b.w) << 16);
    ((uint4*)xb)[i] = o;
  }
}

// transpose+convert weights into 7 slots of Wt[n][k] bf16.
// bf16 LDS tile, stride 66 u16 (odd dword stride -> 2-way-free writes),
// 16B vectorized output stores.
__global__ void k_wt(const void* __restrict__ W0, const void* __restrict__ W1,
                     const void* __restrict__ W2, u16* __restrict__ wt,
                     const int* __restrict__ meta) {
  __shared__ u16 tile[64][66];
  int bid = blockIdx.x;
  int slot = bid >> 10;          // 1024 tiles per slot (32x32 of 64x64)
  int t = bid & 1023;
  int tr = t >> 5, tc = t & 31;
  const void* src; size_t eoff;
  if (slot == 0)      { src = W0; eoff = 0; }
  else if (slot <= 2) { src = W1; eoff = (size_t)(slot-1)*DD*DD; }
  else                { src = W2; eoff = (size_t)(slot-3)*DD*DD; }
  int r0 = tr*64, c0 = tc*64;
  int tid = threadIdx.x;
  int isbf = meta[20];
  #pragma unroll
  for (int i = 0; i < 4; ++i) {
    int idx = tid + i*256;
    int r = idx >> 4, c4 = (idx & 15) * 4;
    size_t goff = eoff + (size_t)(r0 + r)*DD + c0 + c4;
    u16 v0, v1, v2, v3;
    if (isbf) {
      ushort4 v = *(const ushort4*)((const u16*)src + goff);
      v0 = v.x; v1 = v.y; v2 = v.z; v3 = v.w;
    } else {
      float4 v = *(const float4*)((const float*)src + goff);
      v0 = f2bf(v.x); v1 = f2bf(v.y); v2 = f2bf(v.z); v3 = f2bf(v.w);
    }
    tile[r][c4+0] = v0; tile[r][c4+1] = v1;
    tile[r][c4+2] = v2; tile[r][c4+3] = v3;
  }
  __syncthreads();
  u16* dst = wt + (size_t)slot*DD*DD;
  #pragma unroll
  for (int i = 0; i < 2; ++i) {
    int idx = tid + i*256;          // 512 jobs: n = idx>>3, 16B chunk j = idx&7
    int n = idx >> 3, j = idx & 7;
    u16x8 o;
    #pragma unroll
    for (int k = 0; k < 8; ++k) o[k] = tile[j*8 + k][n];
    *(u16x8*)&dst[(size_t)(c0 + n)*DD + r0 + j*8] = o;
  }
}

// ---------------- GEMM: C = relu(A @ W + bias), expert-routed ----------------
// LDS layout: 128 rows x 32 k (u16), 64B/row, with XOR chunk swizzle:
// logical 16B chunk c of row r lives at physical chunk c ^ ((r>>1)&3).
// global_load_lds dest is base+lane*16 (fixed), so the swizzle is applied to
// the per-lane GLOBAL source k-offset instead. Fragment reads then hit bank
// group 16*(cl&1) + 4*(q^((cl>>1)&3)) -> exact 2-way (free, m136).
__global__ __launch_bounds__(256, 2) void k_gemm(
    const u16* __restrict__ A, const u16* __restrict__ Wt,
    const void* __restrict__ bias, const int* __restrict__ perm,
    const int* __restrict__ bases, int nexp,
    void* __restrict__ Out, int final_out, const int* __restrict__ meta) {
  __shared__ __align__(16) u16 As[128*32];
  __shared__ __align__(16) u16 Bs[128*32];

  const int tid  = threadIdx.x;
  const int wid  = tid >> 6;
  const int lane = tid & 63;
  const int m0 = blockIdx.y * 128;   // grid transposed: x=n (16, fastest) for L2
  const int n0 = blockIdx.x * 128;

  int e = 0;
  if (nexp == 2)      e = (m0 >= bases[1]);
  else if (nexp == 4) e = (m0 >= bases[1]) + (m0 >= bases[2]) + (m0 >= bases[3]);
  const u16* W = Wt + (size_t)e * DD * DD;

  // staging: 8 segments of 1024B; wave w pass p -> seg p*4+w.
  const u16* gA[2]; const u16* gB[2];
  u16* lA[2]; u16* lB[2];
  #pragma unroll
  for (int p = 0; p < 2; ++p) {
    int seg   = p*4 + wid;
    int boff  = seg*1024 + lane*16;
    int row   = boff >> 6;
    int chunk = (boff >> 4) & 3;
    int kk    = (chunk ^ ((row >> 1) & 3)) * 8;   // XOR-swizzled source chunk
    int gr = m0 + row;
    if (perm) { int t = perm[gr]; gr = (t < 0) ? 0 : t; }
    gA[p] = A + (size_t)gr * DD + kk;
    gB[p] = W + (size_t)(n0 + row) * DD + kk;
    lA[p] = (u16*)((char*)As + seg*1024);
    lB[p] = (u16*)((char*)Bs + seg*1024);
  }

  f32x4 zero = {0.0f, 0.0f, 0.0f, 0.0f};
  f32x4 acc[4][4];
  #pragma unroll
  for (int i = 0; i < 4; ++i)
    #pragma unroll
    for (int j = 0; j < 4; ++j) acc[i][j] = zero;

  const int wm = wid & 1, wn = wid >> 1;
  const int q = lane >> 4, cl = lane & 15;
  const int sw = q ^ ((cl >> 1) & 3);            // matches store-side swizzle
  const int aoff  = (wm*64 + cl) * 32 + sw*8;
  const int boff2 = (wn*64 + cl) * 32 + sw*8;

  for (int k0 = 0; k0 < DD; k0 += 32) {
    gld16(gA[0] + k0, lA[0]);
    gld16(gA[1] + k0, lA[1]);
    gld16(gB[0] + k0, lB[0]);
    gld16(gB[1] + k0, lB[1]);
    __syncthreads();
    bf16x8 af[4], bf[4];
    #pragma unroll
    for (int mt = 0; mt < 4; ++mt) af[mt] = *(const bf16x8*)&As[aoff + mt*16*32];
    #pragma unroll
    for (int nt = 0; nt < 4; ++nt) bf[nt] = *(const bf16x8*)&Bs[boff2 + nt*16*32];
    #pragma unroll
    for (int mt = 0; mt < 4; ++mt)
      #pragma unroll
      for (int nt = 0; nt < 4; ++nt)
        acc[mt][nt] = __builtin_amdgcn_mfma_f32_16x16x32_bf16(af[mt], bf[nt], acc[mt][nt], 0, 0, 0);
    __syncthreads();
  }

  const int isbf = meta[20];
  float bv[4];
  #pragma unroll
  for (int nt = 0; nt < 4; ++nt) {
    int col = n0 + wn*64 + nt*16 + cl;
    bv[nt] = isbf ? bf2f(((const u16*)bias)[e*DD + col])
                  : ((const float*)bias)[e*DD + col];
  }
  #pragma unroll
  for (int mt = 0; mt < 4; ++mt) {
    int rbase = m0 + wm*64 + mt*16 + q*4;
    #pragma unroll
    for (int r = 0; r < 4; ++r) {
      int row = rbase + r;
      int orow = row;
      if (perm) { orow = perm[row]; if (orow < 0) continue; }
      #pragma unroll
      for (int nt = 0; nt < 4; ++nt) {
        int col = n0 + wn*64 + nt*16 + cl;
        float v = acc[mt][nt][r] + bv[nt];
        v = v > 0.0f ? v : 0.0f;
        if (!final_out || isbf) ((u16*)Out)[(size_t)orow*DD + col] = f2bf(v);
        else                    ((float*)Out)[(size_t)orow*DD + col] = v;
      }
    }
  }
}

extern "C" void kernel_launch(void* const* d_in, const int* in_sizes, int n_in,
                              void* d_out, int out_size, void* d_ws, size_t ws_size,
                              hipStream_t stream) {
  (void)in_sizes; (void)n_in; (void)out_size; (void)ws_size;
  const void* x  = d_in[0];
  const void* W0 = d_in[1];
  const void* b0 = d_in[2];
  const void* W1 = d_in[3];
  const void* b1 = d_in[4];
  const void* W2 = d_in[5];
  const void* b2 = d_in[6];
  const int*  pm = (const int*)d_in[7];

  char* ws  = (char*)d_ws;
  u16*  wt  = (u16*)(ws + OFF_WT);
  u16*  xb  = (u16*)(ws + OFF_XB);   // also reused as h1 after stage0
  u16*  h0  = (u16*)(ws + OFF_H0);
  u16*  h1  = xb;
  int*  p1  = (int*)(ws + OFF_P1);
  int*  p2  = (int*)(ws + OFF_P2);
  int*  meta= (int*)(ws + OFF_META);

  hipLaunchKernelGGL(k_detect, dim3(1),  dim3(256),  0, stream, (const u16*)x, meta);
  hipLaunchKernelGGL(k_route,  dim3(1),  dim3(1024), 0, stream, pm, p1, p2, meta);
  hipLaunchKernelGGL(k_cvtx,   dim3(BB*DD/8/256), dim3(256), 0, stream, x, xb, meta);
  hipLaunchKernelGGL(k_wt,     dim3(7*1024), dim3(256), 0, stream, W0, W1, W2, wt, meta);

  // stage 0: h0 = relu(x @ W0 + b0)
  hipLaunchKernelGGL(k_gemm, dim3(16, 64), dim3(256), 0, stream,
                     xb, wt, b0, (const int*)nullptr, (const int*)nullptr, 1,
                     (void*)h0, 0, meta);
  // stage 1: h1 = relu(h0 @ W1[bit0] + b1[bit0]), rows grouped by bit0
  hipLaunchKernelGGL(k_gemm, dim3(16, 66), dim3(256), 0, stream,
                     h0, wt + (size_t)1*DD*DD, b1, p1, meta + 12, 2,
                     (void*)h1, 0, meta);
  // stage 2: y = relu(h1 @ W2[leaf] + b2[leaf]), rows grouped by leaf
  hipLaunchKernelGGL(k_gemm, dim3(16, 68), dim3(256), 0, stream,
                     h1, wt + (size_t)3*DD*DD, b2, p2, meta + 15, 4,
                     d_out, 1, meta);
}